// Round 1
// baseline (266.543 us; speedup 1.0000x reference)
//
#include <hip/hip_runtime.h>

// ---------------------------------------------------------------------------
// SPP_CNN: conv1d(128->128,K=21,VALID) + BN(eval) + LeakyReLU(0.01)
//          + 2x ragged SPP-max (levels 1,2) + FC(768->2)
// Strategy: bf16 implicit-GEMM conv on MFMA, SPP fused into conv epilogue via
// atomicMax on order-preserving uint keys, tiny FC kernel.
// Workspace layout (needs ~67.9 MB):
//   Xt  : bf16 [32][8192][128]  (x transposed, bf16)          @ 0
//   Wp  : bf16 [21][128][128]   (weights [k][co][ci], bf16)   @ 67108864
//   bnA : f32  [128]                                          @ 67796992
//   bnB : f32  [128]                                          @ 67797504
//   feat: u32  [32][768]        (monotonic float keys)        @ 67798016
// ---------------------------------------------------------------------------

typedef __attribute__((ext_vector_type(4))) float f32x4;
typedef __bf16 bf16x8 __attribute__((ext_vector_type(8)));
typedef unsigned short u16;
typedef unsigned int u32;

#define T_SZ 8192
#define C_SZ 128
#define B_SZ 32
#define KW 21
#define FEAT 768
#define NWIN 6

#define XT_OFF  0
#define WP_OFF  67108864u
#define BNA_OFF 67796992u
#define BNB_OFF 67797504u
#define FK_OFF  67798016u

__device__ __forceinline__ u16 f2bf(float f) {          // f32 -> bf16 RNE
  u32 u = __float_as_uint(f);
  return (u16)((u + 0x7FFFu + ((u >> 16) & 1u)) >> 16);
}

__device__ __forceinline__ u32 fkey(float f) {          // order-preserving
  u32 u = __float_as_uint(f);
  return (u & 0x80000000u) ? ~u : (u | 0x80000000u);
}
__device__ __forceinline__ float funkey(u32 k) {
  u32 u = (k & 0x80000000u) ? (k ^ 0x80000000u) : ~k;
  return __uint_as_float(u);
}

__device__ __forceinline__ void gload_lds16(void* lds, const void* g) {
  __builtin_amdgcn_global_load_lds(
      (const __attribute__((address_space(1))) u32*)g,
      (__attribute__((address_space(3))) u32*)lds, 16, 0, 0);
}

// --------------------------- prep: BN fold ---------------------------------
__global__ void k_prep_bn(const float* g, const float* be, const float* mn,
                          const float* vr, float* bnA, float* bnB) {
  int c = threadIdx.x;
  if (c < C_SZ) {
    float inv = rsqrtf(vr[c] + 1e-5f);
    float a = g[c] * inv;
    bnA[c] = a;
    bnB[c] = be[c] - a * mn[c];
  }
}

// --------------------------- prep: W -> bf16 [k][co][ci] -------------------
__global__ void k_prep_w(const float* __restrict__ W, u16* __restrict__ Wp) {
  int i = blockIdx.x * 256 + threadIdx.x;     // 21*128*128 = 344064
  if (i < KW * C_SZ * C_SZ) {
    int k = i / (C_SZ * C_SZ);
    int r = i - k * C_SZ * C_SZ;
    int co = r >> 7, ci = r & 127;
    Wp[i] = f2bf(W[(co * C_SZ + ci) * KW + k]);
  }
}

// --------------------------- prep: X -> bf16 transposed [b][t][ci] ---------
__global__ void k_prep_xt(const float* __restrict__ X, u16* __restrict__ Xt) {
  __shared__ float tile[C_SZ * 65];           // +1 pad: bank-conflict-free
  const int tid = (int)threadIdx.x;
  const int b = (int)blockIdx.y;
  const int t0 = (int)blockIdx.x * 64;
  const float* Xb = X + (size_t)b * C_SZ * T_SZ;
  {
    const int cw = tid >> 4;                  // 0..15
    const int ch = tid & 15;                  // float4 chunk along t
#pragma unroll
    for (int it = 0; it < 8; ++it) {
      const int ci = it * 16 + cw;
      const f32x4 v = *(const f32x4*)&Xb[(size_t)ci * T_SZ + t0 + ch * 4];
      tile[ci * 65 + ch * 4 + 0] = v.x;
      tile[ci * 65 + ch * 4 + 1] = v.y;
      tile[ci * 65 + ch * 4 + 2] = v.z;
      tile[ci * 65 + ch * 4 + 3] = v.w;
    }
  }
  __syncthreads();
  const int t = tid & 63;
  const int gq = tid >> 6;                    // 32-ci chunk
  u32 wbuf[16];
#pragma unroll
  for (int j = 0; j < 16; ++j) {
    const float lo = tile[(gq * 32 + 2 * j) * 65 + t];
    const float hi = tile[(gq * 32 + 2 * j + 1) * 65 + t];
    wbuf[j] = (u32)f2bf(lo) | ((u32)f2bf(hi) << 16);
  }
  uint4* d4 = (uint4*)(Xt + ((size_t)(b * T_SZ + t0 + t)) * C_SZ + gq * 32);
  d4[0] = make_uint4(wbuf[0], wbuf[1], wbuf[2], wbuf[3]);
  d4[1] = make_uint4(wbuf[4], wbuf[5], wbuf[6], wbuf[7]);
  d4[2] = make_uint4(wbuf[8], wbuf[9], wbuf[10], wbuf[11]);
  d4[3] = make_uint4(wbuf[12], wbuf[13], wbuf[14], wbuf[15]);
}

// --------------------------- conv + bn + leaky + SPP-max -------------------
// Block: 256 thr (4 waves 2x2), tile 128co x 128t, K-loop = 21 taps x 4 ci32.
// LDS rows are 256B; granule (16B) slot XOR-swizzled with (row&7) via
// pre-swizzled global source + linear global_load_lds dest.
__global__ __launch_bounds__(256, 2)
void k_conv(const u16* __restrict__ Xt, const u16* __restrict__ Wp,
            const float* __restrict__ bnA, const float* __restrict__ bnB,
            const int* __restrict__ olen, u32* __restrict__ feat) {
  __shared__ u16 Xs[148 * C_SZ];              // 37888 B
  __shared__ u16 Wk[C_SZ * C_SZ];             // 32768 B
  __shared__ float part[2][NWIN][C_SZ];       //  6144 B  (total 76800)

  const int tid = (int)threadIdx.x;
  const int wid = tid >> 6, lane = tid & 63;
  const int wr = wid >> 1, wc = wid & 1;
  const int l4 = lane & 15, lh = lane >> 4;
  const int b = (int)blockIdx.y;
  const int t0 = (int)blockIdx.x * 128;

  // stage Xs rows 0..147 (1024B = 4 rows per wave-instruction)
  {
    const u16* xb = Xt + (size_t)b * T_SZ * C_SZ;
    for (int i = wid; i < 37; i += 4) {
      const int tt = i * 4 + lh;
      int trow = t0 + tt; trow = trow < T_SZ ? trow : (T_SZ - 1);
      const u16* src = xb + (size_t)trow * C_SZ + ((l4 ^ (tt & 7)) << 3);
      gload_lds16(&Xs[i * 512], src);
    }
  }
  // stage Wk for k=0
  {
    const u16* wb = Wp;
    for (int i = wid; i < 32; i += 4) {
      const int co = i * 4 + lh;
      const u16* src = wb + co * C_SZ + ((l4 ^ (co & 7)) << 3);
      gload_lds16(&Wk[i * 512], src);
    }
  }

  f32x4 acc[4][4];
#pragma unroll
  for (int m = 0; m < 4; ++m)
#pragma unroll
    for (int n = 0; n < 4; ++n) acc[m][n] = (f32x4){0.f, 0.f, 0.f, 0.f};

  for (int k = 0; k < KW; ++k) {
    __syncthreads();                          // staging of Wk(k) (and Xs) done
#pragma unroll
    for (int cb = 0; cb < 4; ++cb) {
      bf16x8 av[4], bv[4];
#pragma unroll
      for (int m = 0; m < 4; ++m) {
        const int co = wr * 64 + m * 16 + l4;
        const int slot = (cb * 4 + lh) ^ (co & 7);
        av[m] = *(const bf16x8*)&Wk[co * C_SZ + (slot << 3)];
      }
#pragma unroll
      for (int n = 0; n < 4; ++n) {
        const int tt = wc * 64 + n * 16 + l4 + k;
        const int slot = (cb * 4 + lh) ^ (tt & 7);
        bv[n] = *(const bf16x8*)&Xs[tt * C_SZ + (slot << 3)];
      }
#pragma unroll
      for (int m = 0; m < 4; ++m)
#pragma unroll
        for (int n = 0; n < 4; ++n)
          acc[m][n] = __builtin_amdgcn_mfma_f32_16x16x32_bf16(
              av[m], bv[n], acc[m][n], 0, 0, 0);
    }
    if (k + 1 < KW) {
      __syncthreads();                        // all reads of Wk(k) done
      const u16* wb = Wp + (k + 1) * (C_SZ * C_SZ);
      for (int i = wid; i < 32; i += 4) {
        const int co = i * 4 + lh;
        const u16* src = wb + co * C_SZ + ((l4 ^ (co & 7)) << 3);
        gload_lds16(&Wk[i * 512], src);
      }
    }
  }

  // ---- epilogue: BN + leaky + 6-window ragged maxes ----
  const int len = olen[b];
  const int L1 = len - (KW - 1);
  const int L2 = len - 2 * (KW - 1);
  int wlo[NWIN], whi[NWIN];
  wlo[0] = 0;       whi[0] = L1;
  wlo[1] = 0;       whi[1] = (L1 + 1) >> 1;
  wlo[2] = L1 >> 1; whi[2] = L1;
  wlo[3] = 0;       whi[3] = L2;
  wlo[4] = 0;       whi[4] = (L2 + 1) >> 1;
  wlo[5] = L2 >> 1; whi[5] = L2;

  float bA[4][4], bB[4][4];
#pragma unroll
  for (int m = 0; m < 4; ++m)
#pragma unroll
    for (int r = 0; r < 4; ++r) {
      const int co = wr * 64 + m * 16 + lh * 4 + r;
      bA[m][r] = bnA[co];
      bB[m][r] = bnB[co];
    }
  int tg[4];
#pragma unroll
  for (int n = 0; n < 4; ++n) tg[n] = t0 + wc * 64 + n * 16 + l4;

#pragma unroll
  for (int m = 0; m < 4; ++m)
#pragma unroll
    for (int n = 0; n < 4; ++n)
#pragma unroll
      for (int r = 0; r < 4; ++r) {
        const float h = bA[m][r] * acc[m][n][r] + bB[m][r];
        acc[m][n][r] = h > 0.f ? h : 0.01f * h;
      }

#pragma unroll
  for (int w = 0; w < NWIN; ++w) {
#pragma unroll
    for (int m = 0; m < 4; ++m)
#pragma unroll
      for (int r = 0; r < 4; ++r) {
        float mx = -__builtin_inff();
#pragma unroll
        for (int n = 0; n < 4; ++n)
          if (tg[n] >= wlo[w] && tg[n] < whi[w]) mx = fmaxf(mx, acc[m][n][r]);
#pragma unroll
        for (int d = 1; d < 16; d <<= 1) mx = fmaxf(mx, __shfl_xor(mx, d));
        if (l4 == 0) part[wc][w][wr * 64 + m * 16 + lh * 4 + r] = mx;
      }
  }
  __syncthreads();
  for (int i = tid; i < NWIN * C_SZ; i += 256) {
    const int w = i >> 7, c = i & 127;
    const float v = fmaxf(part[0][w][c], part[1][w][c]);
    int fi;
    if (w == 0)      fi = c;
    else if (w == 1) fi = 128 + 2 * c;
    else if (w == 2) fi = 129 + 2 * c;
    else if (w == 3) fi = 384 + c;
    else if (w == 4) fi = 512 + 2 * c;
    else             fi = 513 + 2 * c;
    atomicMax(&feat[b * FEAT + fi], fkey(v));
  }
}

// --------------------------- FC head ---------------------------------------
__global__ void k_fc(const u32* __restrict__ feat, const float* __restrict__ fw,
                     const float* __restrict__ fb, float* __restrict__ out) {
  const int bj = (int)blockIdx.x;             // 0..63
  const int b = bj >> 1, j = bj & 1;
  const int lane = (int)threadIdx.x;          // 64
  float s = 0.f;
  for (int i = lane; i < FEAT; i += 64)
    s += funkey(feat[b * FEAT + i]) * fw[j * FEAT + i];
#pragma unroll
  for (int d = 1; d < 64; d <<= 1) s += __shfl_xor(s, d);
  if (lane == 0) out[b * 2 + j] = s + fb[j];
}

// ---------------------------------------------------------------------------
extern "C" void kernel_launch(void* const* d_in, const int* in_sizes, int n_in,
                              void* d_out, int out_size, void* d_ws, size_t ws_size,
                              hipStream_t stream) {
  (void)in_sizes; (void)n_in; (void)out_size; (void)ws_size;
  const float* x     = (const float*)d_in[0];
  const int*   olen  = (const int*)d_in[1];
  const float* w     = (const float*)d_in[2];
  const float* gamma = (const float*)d_in[3];
  const float* beta  = (const float*)d_in[4];
  const float* mean  = (const float*)d_in[5];
  const float* var   = (const float*)d_in[6];
  const float* fw    = (const float*)d_in[7];
  const float* fb    = (const float*)d_in[8];
  float* out = (float*)d_out;

  char* ws = (char*)d_ws;
  u16* Xt   = (u16*)(ws + XT_OFF);
  u16* Wp   = (u16*)(ws + WP_OFF);
  float* bnA = (float*)(ws + BNA_OFF);
  float* bnB = (float*)(ws + BNB_OFF);
  u32* feat = (u32*)(ws + FK_OFF);

  hipMemsetAsync((void*)feat, 0, B_SZ * FEAT * sizeof(u32), stream);
  k_prep_bn<<<1, 128, 0, stream>>>(gamma, beta, mean, var, bnA, bnB);
  k_prep_w<<<1344, 256, 0, stream>>>(w, Wp);
  k_prep_xt<<<dim3(T_SZ / 64, B_SZ), 256, 0, stream>>>(x, Xt);
  k_conv<<<dim3(64, B_SZ), 256, 0, stream>>>(Xt, Wp, bnA, bnB, olen, feat);
  k_fc<<<64, 64, 0, stream>>>(feat, fw, fb, out);
}

// Round 2
// 215.514 us; speedup vs baseline: 1.2368x; 1.2368x over previous
//
#include <hip/hip_runtime.h>

// ---------------------------------------------------------------------------
// SPP_CNN: conv1d(128->128,K=21,VALID) + BN(eval) + LeakyReLU(0.01)
//          + 2x ragged SPP-max (levels 1,2) + FC(768->2)
// R2: barrier-free conv K-loop. W fragments live in registers, loaded
// directly from L2 (wave-coalesced panels), software-pipelined at
// cb-quarter granularity. Only Xt is LDS-staged (once, one barrier).
// Tile 128co x 256t, 4 waves of 64x128, grid 32x32.
// Workspace layout:
//   Xt  : bf16 [32][8192][128]  (x transposed, bf16)          @ 0
//   Wp2 : bf16 [21][2][16][64][8] (W panels [k][wr][f][lane][e]) @ 67108864
//   bnA : f32  [128]                                          @ 67796992
//   bnB : f32  [128]                                          @ 67797504
//   feat: u32  [32][768]        (monotonic float keys)        @ 67798016
// ---------------------------------------------------------------------------

typedef __attribute__((ext_vector_type(4))) float f32x4;
typedef __bf16 bf16x8 __attribute__((ext_vector_type(8)));
typedef unsigned short u16;
typedef unsigned int u32;

#define T_SZ 8192
#define C_SZ 128
#define B_SZ 32
#define KW 21
#define FEAT 768
#define NWIN 6

#define XT_OFF  0
#define WP_OFF  67108864u
#define BNA_OFF 67796992u
#define BNB_OFF 67797504u
#define FK_OFF  67798016u

__device__ __forceinline__ u16 f2bf(float f) {          // f32 -> bf16 RNE
  u32 u = __float_as_uint(f);
  return (u16)((u + 0x7FFFu + ((u >> 16) & 1u)) >> 16);
}

__device__ __forceinline__ u32 fkey(float f) {          // order-preserving
  u32 u = __float_as_uint(f);
  return (u & 0x80000000u) ? ~u : (u | 0x80000000u);
}
__device__ __forceinline__ float funkey(u32 k) {
  u32 u = (k & 0x80000000u) ? (k ^ 0x80000000u) : ~k;
  return __uint_as_float(u);
}

__device__ __forceinline__ void gload_lds16(void* lds, const void* g) {
  __builtin_amdgcn_global_load_lds(
      (const __attribute__((address_space(1))) u32*)g,
      (__attribute__((address_space(3))) u32*)lds, 16, 0, 0);
}

// --------------------------- prep: BN fold ---------------------------------
__global__ void k_prep_bn(const float* g, const float* be, const float* mn,
                          const float* vr, float* bnA, float* bnB) {
  int c = threadIdx.x;
  if (c < C_SZ) {
    float inv = rsqrtf(vr[c] + 1e-5f);
    float a = g[c] * inv;
    bnA[c] = a;
    bnB[c] = be[c] - a * mn[c];
  }
}

// --------------------------- prep: W -> bf16 wave panels -------------------
// Wp2 element index: (((k*2 + wr)*16 + f)*64 + lane)*8 + e
//   f = cb*4 + m ; lane = lh*16 + l4
//   maps W[co = wr*64 + m*16 + l4][ci = cb*32 + lh*8 + e][k]
__global__ void k_prep_w(const float* __restrict__ W, u16* __restrict__ Wp2) {
  int i = blockIdx.x * 256 + threadIdx.x;     // 21*2*16*64*8 = 344064
  if (i < KW * 2 * 16 * 64 * 8) {
    const int k = i >> 14;                    // /16384
    const int r = i & 16383;
    const int wr = r >> 13;
    const int f = (r >> 9) & 15;
    const int lane = (r >> 3) & 63;
    const int e = r & 7;
    const int m = f & 3, cb = f >> 2;
    const int l4 = lane & 15, lh = lane >> 4;
    const int co = wr * 64 + m * 16 + l4;
    const int ci = cb * 32 + lh * 8 + e;
    Wp2[i] = f2bf(W[(co * C_SZ + ci) * KW + k]);
  }
}

// --------------------------- prep: X -> bf16 transposed [b][t][ci] ---------
__global__ void k_prep_xt(const float* __restrict__ X, u16* __restrict__ Xt) {
  __shared__ float tile[C_SZ * 65];           // +1 pad: bank-conflict-free
  const int tid = (int)threadIdx.x;
  const int b = (int)blockIdx.y;
  const int t0 = (int)blockIdx.x * 64;
  const float* Xb = X + (size_t)b * C_SZ * T_SZ;
  {
    const int cw = tid >> 4;                  // 0..15
    const int ch = tid & 15;                  // float4 chunk along t
#pragma unroll
    for (int it = 0; it < 8; ++it) {
      const int ci = it * 16 + cw;
      const f32x4 v = *(const f32x4*)&Xb[(size_t)ci * T_SZ + t0 + ch * 4];
      tile[ci * 65 + ch * 4 + 0] = v.x;
      tile[ci * 65 + ch * 4 + 1] = v.y;
      tile[ci * 65 + ch * 4 + 2] = v.z;
      tile[ci * 65 + ch * 4 + 3] = v.w;
    }
  }
  __syncthreads();
  const int t = tid & 63;
  const int gq = tid >> 6;                    // 32-ci chunk
  u32 wbuf[16];
#pragma unroll
  for (int j = 0; j < 16; ++j) {
    const float lo = tile[(gq * 32 + 2 * j) * 65 + t];
    const float hi = tile[(gq * 32 + 2 * j + 1) * 65 + t];
    wbuf[j] = (u32)f2bf(lo) | ((u32)f2bf(hi) << 16);
  }
  uint4* d4 = (uint4*)(Xt + ((size_t)(b * T_SZ + t0 + t)) * C_SZ + gq * 32);
  d4[0] = make_uint4(wbuf[0], wbuf[1], wbuf[2], wbuf[3]);
  d4[1] = make_uint4(wbuf[4], wbuf[5], wbuf[6], wbuf[7]);
  d4[2] = make_uint4(wbuf[8], wbuf[9], wbuf[10], wbuf[11]);
  d4[3] = make_uint4(wbuf[12], wbuf[13], wbuf[14], wbuf[15]);
}

// --------------------------- conv + bn + leaky + SPP-max -------------------
// Block 256 thr (4 waves, wr x wc = 2x2), tile 128co x 256t; wave 64co x 128t.
// Barrier-free K-loop: av from registers (L2-coalesced panel loads,
// pipelined one tap ahead at cb granularity), bv from swizzled Xs LDS.
__global__ __launch_bounds__(256, 2)
void k_conv(const u16* __restrict__ Xt, const u16* __restrict__ Wp2,
            const float* __restrict__ bnA, const float* __restrict__ bnB,
            const int* __restrict__ olen, u32* __restrict__ feat) {
  __shared__ u16 Xs[276 * C_SZ];              // 70656 B
  __shared__ float part[2][NWIN][C_SZ];       //  6144 B  (total 76800)

  const int tid = (int)threadIdx.x;
  const int wid = tid >> 6, lane = tid & 63;
  const int wr = wid >> 1, wc = wid & 1;
  const int l4 = lane & 15, lh = lane >> 4;
  const int b = (int)blockIdx.y;
  const int t0 = (int)blockIdx.x * 256;

  // ---- prefetch W panels for tap 0 into registers ----
  bf16x8 av[4][4];
  {
    const u16* wb = Wp2 + ((size_t)wr << 13) + (lane << 3);
#pragma unroll
    for (int cb = 0; cb < 4; ++cb)
#pragma unroll
      for (int m = 0; m < 4; ++m)
        av[cb][m] = *(const bf16x8*)&wb[((cb << 2) + m) << 9];
  }

  // ---- stage Xs rows 0..275 (4 rows = 1024B per wave-instruction) ----
  {
    const u16* xb = Xt + (size_t)b * T_SZ * C_SZ;
    for (int i = wid; i < 69; i += 4) {
      const int tt = i * 4 + lh;
      int trow = t0 + tt; trow = trow < T_SZ ? trow : (T_SZ - 1);
      const u16* src = xb + (size_t)trow * C_SZ + ((l4 ^ (tt & 7)) << 3);
      gload_lds16(&Xs[i * 512], src);
    }
  }
  __syncthreads();                            // the only barrier before epilogue

  f32x4 acc[4][8];
#pragma unroll
  for (int m = 0; m < 4; ++m)
#pragma unroll
    for (int n = 0; n < 8; ++n) acc[m][n] = (f32x4){0.f, 0.f, 0.f, 0.f};

  const int rowc = wc * 128 + l4;
  for (int k = 0; k < KW; ++k) {
    const int kn = (k + 1 < KW) ? (k + 1) : k;
    const int rowb = rowc + k;
    const u16* wb = Wp2 + (((size_t)(kn * 2 + wr)) << 13) + (lane << 3);
#pragma unroll
    for (int cb = 0; cb < 4; ++cb) {
      const u16* xp = &Xs[(rowb << 7) + ((((cb << 2) + lh) ^ (rowb & 7)) << 3)];
#pragma unroll
      for (int nh = 0; nh < 2; ++nh) {
        bf16x8 bv[4];
#pragma unroll
        for (int n = 0; n < 4; ++n)
          bv[n] = *(const bf16x8*)&xp[(nh * 64 + n * 16) << 7];
#pragma unroll
        for (int m = 0; m < 4; ++m)
#pragma unroll
          for (int n = 0; n < 4; ++n)
            acc[m][nh * 4 + n] = __builtin_amdgcn_mfma_f32_16x16x32_bf16(
                av[cb][m], bv[n], acc[m][nh * 4 + n], 0, 0, 0);
      }
      // prefetch this cb-quarter of next tap (WAR-ordered after last use)
#pragma unroll
      for (int m = 0; m < 4; ++m)
        av[cb][m] = *(const bf16x8*)&wb[((cb << 2) + m) << 9];
    }
  }

  // ---- epilogue: BN + leaky + 6-window ragged maxes ----
  const int len = olen[b];
  const int L1 = len - (KW - 1);
  const int L2 = len - 2 * (KW - 1);
  int wlo[NWIN], whi[NWIN];
  wlo[0] = 0;       whi[0] = L1;
  wlo[1] = 0;       whi[1] = (L1 + 1) >> 1;
  wlo[2] = L1 >> 1; whi[2] = L1;
  wlo[3] = 0;       whi[3] = L2;
  wlo[4] = 0;       whi[4] = (L2 + 1) >> 1;
  wlo[5] = L2 >> 1; whi[5] = L2;

  float bA[4][4], bB[4][4];
#pragma unroll
  for (int m = 0; m < 4; ++m)
#pragma unroll
    for (int r = 0; r < 4; ++r) {
      const int co = wr * 64 + m * 16 + lh * 4 + r;
      bA[m][r] = bnA[co];
      bB[m][r] = bnB[co];
    }
  int tg[8];
#pragma unroll
  for (int j = 0; j < 8; ++j)
    tg[j] = t0 + wc * 128 + (j >> 2) * 64 + (j & 3) * 16 + l4;

#pragma unroll
  for (int m = 0; m < 4; ++m)
#pragma unroll
    for (int j = 0; j < 8; ++j)
#pragma unroll
      for (int r = 0; r < 4; ++r) {
        const float h = bA[m][r] * acc[m][j][r] + bB[m][r];
        acc[m][j][r] = h > 0.f ? h : 0.01f * h;
      }

#pragma unroll
  for (int w = 0; w < NWIN; ++w) {
#pragma unroll
    for (int m = 0; m < 4; ++m)
#pragma unroll
      for (int r = 0; r < 4; ++r) {
        float mx = -__builtin_inff();
#pragma unroll
        for (int j = 0; j < 8; ++j)
          if (tg[j] >= wlo[w] && tg[j] < whi[w]) mx = fmaxf(mx, acc[m][j][r]);
#pragma unroll
        for (int d = 1; d < 16; d <<= 1) mx = fmaxf(mx, __shfl_xor(mx, d));
        if (l4 == 0) part[wc][w][wr * 64 + m * 16 + lh * 4 + r] = mx;
      }
  }
  __syncthreads();
  for (int i = tid; i < NWIN * C_SZ; i += 256) {
    const int w = i >> 7, c = i & 127;
    const float v = fmaxf(part[0][w][c], part[1][w][c]);
    int fi;
    if (w == 0)      fi = c;
    else if (w == 1) fi = 128 + 2 * c;
    else if (w == 2) fi = 129 + 2 * c;
    else if (w == 3) fi = 384 + c;
    else if (w == 4) fi = 512 + 2 * c;
    else             fi = 513 + 2 * c;
    atomicMax(&feat[b * FEAT + fi], fkey(v));
  }
}

// --------------------------- FC head ---------------------------------------
__global__ void k_fc(const u32* __restrict__ feat, const float* __restrict__ fw,
                     const float* __restrict__ fb, float* __restrict__ out) {
  const int bj = (int)blockIdx.x;             // 0..63
  const int b = bj >> 1, j = bj & 1;
  const int lane = (int)threadIdx.x;          // 64
  float s = 0.f;
  for (int i = lane; i < FEAT; i += 64)
    s += funkey(feat[b * FEAT + i]) * fw[j * FEAT + i];
#pragma unroll
  for (int d = 1; d < 64; d <<= 1) s += __shfl_xor(s, d);
  if (lane == 0) out[b * 2 + j] = s + fb[j];
}

// ---------------------------------------------------------------------------
extern "C" void kernel_launch(void* const* d_in, const int* in_sizes, int n_in,
                              void* d_out, int out_size, void* d_ws, size_t ws_size,
                              hipStream_t stream) {
  (void)in_sizes; (void)n_in; (void)out_size; (void)ws_size;
  const float* x     = (const float*)d_in[0];
  const int*   olen  = (const int*)d_in[1];
  const float* w     = (const float*)d_in[2];
  const float* gamma = (const float*)d_in[3];
  const float* beta  = (const float*)d_in[4];
  const float* mean  = (const float*)d_in[5];
  const float* var   = (const float*)d_in[6];
  const float* fw    = (const float*)d_in[7];
  const float* fb    = (const float*)d_in[8];
  float* out = (float*)d_out;

  char* ws = (char*)d_ws;
  u16* Xt   = (u16*)(ws + XT_OFF);
  u16* Wp2  = (u16*)(ws + WP_OFF);
  float* bnA = (float*)(ws + BNA_OFF);
  float* bnB = (float*)(ws + BNB_OFF);
  u32* feat = (u32*)(ws + FK_OFF);

  hipMemsetAsync((void*)feat, 0, B_SZ * FEAT * sizeof(u32), stream);
  k_prep_bn<<<1, 128, 0, stream>>>(gamma, beta, mean, var, bnA, bnB);
  k_prep_w<<<1344, 256, 0, stream>>>(w, Wp2);
  k_prep_xt<<<dim3(T_SZ / 64, B_SZ), 256, 0, stream>>>(x, Xt);
  k_conv<<<dim3(T_SZ / 256, B_SZ), 256, 0, stream>>>(Xt, Wp2, bnA, bnB, olen, feat);
  k_fc<<<64, 64, 0, stream>>>(feat, fw, fb, out);
}